// Round 4
// baseline (380.874 us; speedup 1.0000x reference)
//
#include <hip/hip_runtime.h>
#include <hip/hip_bf16.h>

typedef __bf16 bf16x8 __attribute__((ext_vector_type(8)));
typedef float f32x4 __attribute__((ext_vector_type(4)));

static constexpr int Tn = 8192;
static constexpr int Cn = 1024;

#define DEVI __device__ __forceinline__

DEVI float bf2f(ushort u) { union { uint i; float f; } c; c.i = ((uint)u) << 16; return c.f; }
DEVI ushort f2bf(float f) {
  uint x = __builtin_bit_cast(uint, f);
  x += 0x7fffu + ((x >> 16) & 1u);   // RNE
  return (ushort)(x >> 16);
}

typedef const __attribute__((address_space(1))) void glb_v;
typedef __attribute__((address_space(3))) void lds_v;

#define BAR()   __builtin_amdgcn_s_barrier()
#define SCH0()  __builtin_amdgcn_sched_barrier(0)
#define LGK0()  asm volatile("s_waitcnt lgkmcnt(0)" ::: "memory")
#define VMD0()  asm volatile("s_waitcnt vmcnt(0)" ::: "memory")
#define PRIO1() __builtin_amdgcn_s_setprio(1)
#define PRIO0() __builtin_amdgcn_s_setprio(0)

// ---------------------------------------------------------------- cast + concat
__global__ __launch_bounds__(256) void cast_all(
    const float* __restrict__ x, const float* __restrict__ wq, const float* __restrict__ wk,
    const float* __restrict__ wv, const float* __restrict__ wp,
    const float* __restrict__ bq, const float* __restrict__ bk, const float* __restrict__ bv,
    ushort* __restrict__ xb, ushort* __restrict__ wqkv, ushort* __restrict__ wpb,
    float* __restrict__ bqkv)
{
  const long long NX = (long long)Tn * Cn;
  const long long NW = (long long)Cn * Cn;      // 2^20
  if (blockIdx.x >= 12288) {   // bias concat
    int id = ((blockIdx.x - 12288) * 256 + threadIdx.x) * 4;
#pragma unroll
    for (int e = 0; e < 4; ++e) {
      int j = id + e;
      if (j < 3 * Cn) bqkv[j] = j < Cn ? bq[j] : (j < 2 * Cn ? bk[j - Cn] : bv[j - 2 * Cn]);
    }
    return;
  }
  long long i = ((long long)blockIdx.x * 256 + threadIdx.x) * 4;
  const float* src; ushort* dst; long long off;
  if (i < NX) { src = x; dst = xb; off = i; }
  else {
    long long r = i - NX; int seg = (int)(r >> 20); off = r & (NW - 1);
    if (seg < 3) { src = seg == 0 ? wq : seg == 1 ? wk : wv; dst = wqkv + (size_t)seg * NW; }
    else         { src = wp; dst = wpb; }
  }
  float4 v = *reinterpret_cast<const float4*>(src + off);
  ushort4 o; o.x = f2bf(v.x); o.y = f2bf(v.y); o.z = f2bf(v.z); o.w = f2bf(v.w);
  *reinterpret_cast<ushort4*>(dst + off) = o;
}

// ---------------------------------------------------------------- 8-phase GEMM (m201-template port)
// C[M,N] = A[M,K] @ Bt[N,K]^T, bf16 in, fp32 acc.  BK=64, 4 or 8 waves (WMx4),
// per-wave C = 128 x (BN/4).  LDS halves map to within-wave quadrants:
//   A half h = row bit6; slot sr = ((R>>7)<<6)|(R&63)   (so Mlo quadrant = h0)
//   B half h = col bit(GSB); slot = ((C>>GSB)<<GSB)|(C&mask)
// Per 2-K-tile iteration, 8 phases; each phase: {ds-reads | stage 1 half ->
// BAR -> lgkmcnt(0) -> setprio(1) -> MFMA quadrant -> setprio(0) -> BAR}.
// Stage ledger (tile t in buf0, t+1 in buf1):
//   ph1: Blo(t+1),Ahi(t+1)  ph3: Alo(t+2)  ph4: Bhi(t+2)+VMW
//   ph5: Ahi(t+2)           ph6: Blo(t+2)  ph7: Alo(t+3)  ph8: Bhi(t+3)+VMW
// Each stage lands >=1 barrier-pair after its slot's last ds_read (reads of a
// half happen in exactly one phase; drained by that phase's lgkmcnt(0)).
// VMW = vmcnt(LA+LB) proves: at ph4, all 4 halves of t+1 landed (needed ph5-8);
// at ph8, all 4 halves of t+2 landed (needed ph1'-4').  Never vmcnt(0) in-loop.
template<int BM, int BN, int NTHR, bool OUT_BF16, bool HAS_BIAS, bool CAUSAL, bool PVMODE>
__global__ __launch_bounds__(NTHR, 2)
void gemm8p(const ushort* __restrict__ A, const ushort* __restrict__ Bt,
            const float* __restrict__ bias, void* __restrict__ outp,
            int K, int lda, int ldb, int ldc, float scale)
{
  constexpr int NB2 = BN / 128;           // N-frags per quadrant (2 or 1)
  constexpr int GSB = (BN == 256) ? 5 : 4;
  constexpr int ASZ = (BM / 2) * 64;      // elems per A half
  constexpr int BSZ = (BN / 2) * 64;
  constexpr int TOT = 2 * (ASZ + BSZ);
  constexpr int LA = ASZ / (NTHR * 8);    // global_load_lds per thread per A half
  constexpr int LB = BSZ / (NTHR * 8);
  static_assert(LA >= 1 && LB >= 1, "geometry");

  __shared__ __align__(16) ushort sm[2 * TOT];

  const int tid = threadIdx.x, lane = tid & 63, wid = tid >> 6;
  const int wm = wid >> 2, wn = wid & 3;
  const int ln15 = lane & 15, lsec = lane >> 4;
  const int bx = blockIdx.x;
  if (CAUSAL && (int)blockIdx.y < bx) return;
  const int col0 = bx * BN;

  auto VMW = [] {
    if constexpr (LA + LB == 4) asm volatile("s_waitcnt vmcnt(4)" ::: "memory");
    else if constexpr (LA + LB == 3) asm volatile("s_waitcnt vmcnt(3)" ::: "memory");
    else static_assert(LA + LB == 4 || LA + LB == 3, "vmcnt");
  };

  constexpr int NPASS = PVMODE ? 2 : 1;
  for (int pr = 0; pr < NPASS; ++pr) {
    const int by = PVMODE ? (pr == 0 ? (2 * (int)gridDim.y - 1 - (int)blockIdx.y)
                                     : (int)blockIdx.y)
                          : (int)blockIdx.y;
    const int rowA0 = by * BM;
    int NT = K >> 6;
    if (PVMODE) { int kl = (by + 1) * BM; if (kl < K) NT = kl >> 6; }

    if (pr) { VMD0(); BAR(); }   // drain pass-1 tail stages before LDS reuse

    auto stA = [&](int t, int b, int h) {
      const int tt = t < NT ? t : NT - 1;
      const int k0 = tt << 6;
#pragma unroll
      for (int i = 0; i < LA; ++i) {
        int s = tid + i * NTHR;
        int sr = s >> 3;
        int R = ((sr >> 6) << 7) | (h << 6) | (sr & 63);
        int kc = (s & 7) ^ (sr & 7);
        const ushort* g = A + (size_t)(rowA0 + R) * (size_t)lda + (k0 + kc * 8);
        __builtin_amdgcn_global_load_lds((glb_v*)g, (lds_v*)(&sm[b * TOT + h * ASZ + s * 8]), 16, 0, 0);
      }
    };
    auto stB = [&](int t, int b, int h) {
      const int tt = t < NT ? t : NT - 1;
      const int k0 = tt << 6;
#pragma unroll
      for (int i = 0; i < LB; ++i) {
        int s = tid + i * NTHR;
        int sr = s >> 3;
        int Cg = ((sr >> GSB) << (GSB + 1)) | (h << GSB) | (sr & ((1 << GSB) - 1));
        int kc = (s & 7) ^ (sr & 7);
        const ushort* g = Bt + (size_t)(col0 + Cg) * (size_t)ldb + (k0 + kc * 8);
        __builtin_amdgcn_global_load_lds((glb_v*)g, (lds_v*)(&sm[b * TOT + 2 * ASZ + h * BSZ + s * 8]), 16, 0, 0);
      }
    };

    bf16x8 Ar[8], Bl[2 * NB2], Bh2[2 * NB2];
    auto rdA = [&](int b, int h) {
#pragma unroll
      for (int mi = 0; mi < 4; ++mi)
#pragma unroll
        for (int ks = 0; ks < 2; ++ks) {
          int sr = wm * 64 + mi * 16 + ln15;
          int kc = ks * 4 + lsec;
          Ar[mi * 2 + ks] = *reinterpret_cast<const bf16x8*>(
              &sm[b * TOT + h * ASZ + (sr * 8 + (kc ^ (sr & 7))) * 8]);
        }
    };
    auto rdB = [&](int b, int h, bf16x8* Bf) {
#pragma unroll
      for (int ni = 0; ni < NB2; ++ni)
#pragma unroll
        for (int ks = 0; ks < 2; ++ks) {
          int sr = wn * (1 << GSB) + ni * 16 + ln15;
          int kc = ks * 4 + lsec;
          Bf[ni * 2 + ks] = *reinterpret_cast<const bf16x8*>(
              &sm[b * TOT + 2 * ASZ + h * BSZ + (sr * 8 + (kc ^ (sr & 7))) * 8]);
        }
    };

    f32x4 acc[8][2 * NB2];
#pragma unroll
    for (int i = 0; i < 8; ++i)
#pragma unroll
      for (int j = 0; j < 2 * NB2; ++j) acc[i][j] = f32x4{0.f, 0.f, 0.f, 0.f};

    auto quad = [&](int mq, int nq, bf16x8* Bf) {
#pragma unroll
      for (int mi = 0; mi < 4; ++mi)
#pragma unroll
        for (int ni = 0; ni < NB2; ++ni)
#pragma unroll
          for (int ks = 0; ks < 2; ++ks)
            acc[mq * 4 + mi][nq * NB2 + ni] = __builtin_amdgcn_mfma_f32_16x16x32_bf16(
                Ar[mi * 2 + ks], Bf[ni * 2 + ks], acc[mq * 4 + mi][nq * NB2 + ni], 0, 0, 0);
    };

    // ---- prologue: tile0 all 4 halves; Alo(1), Bhi(1) stay in flight
    stA(0, 0, 0); stA(0, 0, 1); stB(0, 0, 0); stB(0, 0, 1);
    stA(1, 1, 0); stB(1, 1, 1);
    VMW(); BAR();

    const int NG = NT >> 1;
    for (int g = 0; g < NG; ++g) {
      const int t = 2 * g;
      // ph1: t(buf0) Mlo,Nlo | stage Blo(t+1),Ahi(t+1) -> buf1
      rdA(0, 0); rdB(0, 0, Bl); stB(t + 1, 1, 0); stA(t + 1, 1, 1);
      BAR(); LGK0(); SCH0(); PRIO1(); quad(0, 0, Bl); PRIO0(); BAR();
      // ph2: Mlo,Nhi
      rdB(0, 1, Bh2);
      BAR(); LGK0(); SCH0(); PRIO1(); quad(0, 1, Bh2); PRIO0(); BAR();
      // ph3: Mhi,Nhi | stage Alo(t+2) -> buf0
      rdA(0, 1); stA(t + 2, 0, 0);
      BAR(); LGK0(); SCH0(); PRIO1(); quad(1, 1, Bh2); PRIO0(); BAR();
      // ph4: Mhi,Nlo | stage Bhi(t+2) -> buf0 | counted wait: t+1 landed
      stB(t + 2, 0, 1); VMW();
      BAR(); SCH0(); PRIO1(); quad(1, 0, Bl); PRIO0(); BAR();
      // ph5: t+1(buf1) Mlo,Nlo | stage Ahi(t+2) -> buf0
      rdA(1, 0); rdB(1, 0, Bl); stA(t + 2, 0, 1);
      BAR(); LGK0(); SCH0(); PRIO1(); quad(0, 0, Bl); PRIO0(); BAR();
      // ph6: Mlo,Nhi | stage Blo(t+2) -> buf0
      rdB(1, 1, Bh2); stB(t + 2, 0, 0);
      BAR(); LGK0(); SCH0(); PRIO1(); quad(0, 1, Bh2); PRIO0(); BAR();
      // ph7: Mhi,Nhi | stage Alo(t+3) -> buf1
      rdA(1, 1); stA(t + 3, 1, 0);
      BAR(); LGK0(); SCH0(); PRIO1(); quad(1, 1, Bh2); PRIO0(); BAR();
      // ph8: Mhi,Nlo | stage Bhi(t+3) -> buf1 | counted wait: t+2 landed
      stB(t + 3, 1, 1); VMW();
      BAR(); SCH0(); PRIO1(); quad(1, 0, Bl); PRIO0(); BAR();
    }

    // ---- epilogue: C col = lane&15 (+16*frag), row = lsec*4 + j
#pragma unroll
    for (int mi8 = 0; mi8 < 8; ++mi8)
#pragma unroll
      for (int nj = 0; nj < 2 * NB2; ++nj) {
        int col;
        if constexpr (NB2 == 2) col = col0 + wn * 64 + (nj >> 1) * 32 + (nj & 1) * 16 + ln15;
        else                    col = col0 + wn * 32 + nj * 16 + ln15;
        float bv = HAS_BIAS ? bias[col] : 0.f;
        const int r0 = rowA0 + wm * 128 + (mi8 >> 2) * 64 + (mi8 & 3) * 16 + lsec * 4;
        f32x4 v = acc[mi8][nj];
#pragma unroll
        for (int j = 0; j < 4; ++j) {
          float val = v[j] * scale + bv;
          if (OUT_BF16) ((ushort*)outp)[(size_t)(r0 + j) * (size_t)ldc + col] = f2bf(val);
          else          ((float*)outp)[(size_t)(r0 + j) * (size_t)ldc + col] = val;
        }
      }
  }
  VMD0();   // clamped tail stages must land before LDS is reassigned
}

// ---------------------------------------------------------------- transpose (bf16), 64x64 tiles
__global__ __launch_bounds__(256) void transpose64(const ushort* __restrict__ in,
                                                   ushort* __restrict__ out,
                                                   int ldin, int ldout)
{
  __shared__ ushort tile[64][65];
  const int c0 = blockIdx.x * 64, r0 = blockIdx.y * 64;
  const int t = threadIdx.x;
#pragma unroll
  for (int i = t; i < 512; i += 256) {
    int r = i >> 3, kc = i & 7;
    uint4 v = *reinterpret_cast<const uint4*>(in + (size_t)(r0 + r) * ldin + c0 + kc * 8);
    const ushort* u = reinterpret_cast<const ushort*>(&v);
#pragma unroll
    for (int j = 0; j < 8; ++j) tile[r][kc * 8 + j] = u[j];
  }
  __syncthreads();
#pragma unroll
  for (int i = t; i < 512; i += 256) {
    int c = i >> 3, rc = i & 7;
    union { uint4 v; ushort u[8]; } pk;
#pragma unroll
    for (int j = 0; j < 8; ++j) pk.u[j] = tile[rc * 8 + j][c];
    *reinterpret_cast<uint4*>(out + (size_t)(c0 + c) * ldout + r0 + rc * 8) = pk.v;
  }
}

// ---------------------------------------------------------------- causal softmax, in place
__global__ __launch_bounds__(256) void softmax_causal(ushort* __restrict__ S, int Td)
{
  const int t = blockIdx.x;
  const int tid = threadIdx.x;
  ushort* row = S + (size_t)t * Td;
  const int L = t + 1;
  const int Lv = L & ~7;

  float sum = 0.f;
  for (int j = tid * 8; j < Lv; j += 2048) {
    uint4 v = *reinterpret_cast<const uint4*>(row + j);
    const ushort* u = reinterpret_cast<const ushort*>(&v);
#pragma unroll
    for (int e = 0; e < 8; ++e) sum += __expf(bf2f(u[e]));
  }
  for (int j = Lv + tid; j < L; j += 256) sum += __expf(bf2f(row[j]));

#pragma unroll
  for (int off = 32; off; off >>= 1) sum += __shfl_down(sum, off);
  __shared__ float red[4];
  if ((tid & 63) == 0) red[tid >> 6] = sum;
  __syncthreads();
  const float inv = 1.f / (red[0] + red[1] + red[2] + red[3]);

  for (int j = tid * 8; j < Lv; j += 2048) {
    uint4 v = *reinterpret_cast<const uint4*>(row + j);
    union { uint4 v; ushort u[8]; } pk;
    const ushort* u = reinterpret_cast<const ushort*>(&v);
#pragma unroll
    for (int e = 0; e < 8; ++e) pk.u[e] = f2bf(__expf(bf2f(u[e])) * inv);
    *reinterpret_cast<uint4*>(row + j) = pk.v;
  }
  for (int j = Lv + tid; j < L; j += 256) row[j] = f2bf(__expf(bf2f(row[j])) * inv);

  const int Za = (L + 7) & ~7;
  for (int j = L + tid; j < Za; j += 256) row[j] = 0;
  uint4 z; z.x = z.y = z.z = z.w = 0u;
  for (int j = Za + tid * 8; j < Td; j += 2048) *reinterpret_cast<uint4*>(row + j) = z;
}

// ---------------------------------------------------------------- launch
extern "C" void kernel_launch(void* const* d_in, const int* in_sizes, int n_in,
                              void* d_out, int out_size, void* d_ws, size_t ws_size,
                              hipStream_t stream)
{
  (void)in_sizes; (void)n_in; (void)out_size; (void)ws_size;
  const float* x  = (const float*)d_in[0];
  const float* Wq = (const float*)d_in[1];
  const float* bq = (const float*)d_in[2];
  const float* Wk = (const float*)d_in[3];
  const float* bk = (const float*)d_in[4];
  const float* Wv = (const float*)d_in[5];
  const float* bv = (const float*)d_in[6];
  const float* Wp = (const float*)d_in[7];
  const float* bp = (const float*)d_in[8];

  char* w = (char*)d_ws;
  const size_t TC = (size_t)Tn * Cn * 2, CC = (size_t)Cn * Cn * 2;
  ushort* xb   = (ushort*)w; w += TC;                    // 16 MB
  ushort* Wqkv = (ushort*)w; w += 3 * CC;                // 6 MB
  ushort* wpb  = (ushort*)w; w += CC;                    // 2 MB
  float*  bqkv = (float*)w;  w += 3 * Cn * 4 + 4096;     // 12 KB
  ushort* QKV  = (ushort*)w; w += 3 * TC;                // 48 MB
  ushort* Vt   = (ushort*)w; w += TC;                    // 16 MB
  ushort* Yb   = (ushort*)w; w += TC;                    // 16 MB
  ushort* S    = (ushort*)w; w += (size_t)Tn * Tn * 2;   // 128 MB

  cast_all<<<12291, 256, 0, stream>>>(x, Wq, Wk, Wv, Wp, bq, bk, bv, xb, Wqkv, wpb, bqkv);

  // QKV fused: [8192,3072] = xb @ Wqkv^T + bqkv   (grid 768 = 3 exact rounds)
  gemm8p<256, 128, 512, true, true, false, false><<<dim3(24, 32), 512, 0, stream>>>(
      xb, Wqkv, bqkv, QKV, Cn, Cn, Cn, 3 * Cn, 1.0f);

  // V^T for the PV GEMM
  transpose64<<<dim3(Cn / 64, Tn / 64), 256, 0, stream>>>(QKV + 2 * Cn, Vt, 3 * Cn, Tn);

  // S = Q @ K^T / 32  (256^2 tiles, causal skip: 528 active blocks)
  gemm8p<256, 256, 512, true, false, true, false><<<dim3(32, 32), 512, 0, stream>>>(
      QKV, QKV + Cn, nullptr, S, Cn, 3 * Cn, 3 * Cn, Tn, 0.03125f);

  softmax_causal<<<Tn, 256, 0, stream>>>(S, Tn);

  // Y = P @ V  (128^2, 4 waves, 2 blocks/CU; paired rows 63-gy then gy ->
  //             constant 130 K-tiles per block, single round of 256 blocks)
  gemm8p<128, 128, 256, true, false, false, true><<<dim3(8, 32), 256, 0, stream>>>(
      S, Vt, nullptr, Yb, Tn, Tn, Tn, Cn, 1.0f);

  // out = Y @ Wp^T + bp   (fp32 out, grid 256 = 1 exact round)
  gemm8p<256, 128, 512, false, true, false, false><<<dim3(8, 32), 512, 0, stream>>>(
      Yb, wpb, bp, d_out, Cn, Cn, Cn, Cn, 1.0f);
}